// Round 6
// baseline (154.027 us; speedup 1.0000x reference)
//
#include <hip/hip_runtime.h>

typedef __attribute__((ext_vector_type(8))) short short8;
typedef __attribute__((ext_vector_type(4))) float f32x4;

// ---------- helpers ----------
__device__ __forceinline__ unsigned short f2bf(float f) {
  unsigned u = __builtin_bit_cast(unsigned, f);
  u += 0x7fffu + ((u >> 16) & 1u);   // RNE
  return (unsigned short)(u >> 16);
}
__device__ __forceinline__ unsigned pack_bf2(float lo, float hi) {
  return (unsigned)f2bf(lo) | ((unsigned)f2bf(hi) << 16);
}

#define GLDS16(g, l)                                                          \
  __builtin_amdgcn_global_load_lds(                                           \
      (const __attribute__((address_space(1))) void*)(g),                     \
      (__attribute__((address_space(3))) void*)(l), 16, 0, 0)

// Q pre-scale: HEAD_DIM^-0.5 * log2(e), so softmax uses exp2 directly.
#define QSCALE 0.18033688011112042f

// ---------- cast x (fp32 -> bf16), vectorized ----------
__global__ void cast_x_bf16(const float4* __restrict__ in,
                            ushort4* __restrict__ out, int n4) {
  int i = blockIdx.x * blockDim.x + threadIdx.x;
  if (i >= n4) return;
  float4 v = in[i];
  ushort4 o;
  o.x = f2bf(v.x); o.y = f2bf(v.y); o.z = f2bf(v.z); o.w = f2bf(v.w);
  out[i] = o;
}

// ---------- fused transpose+convert of all weights (one launch) ----------
__global__ void transpose_cvt_all(const float* __restrict__ Wq,
                                  const float* __restrict__ Wk,
                                  const float* __restrict__ Wv,
                                  const float* __restrict__ Wo,
                                  unsigned short* __restrict__ Wcat,
                                  unsigned short* __restrict__ Wot) {
  __shared__ float tile[32][33];
  const int z = blockIdx.z;
  int bx = blockIdx.x;
  const float* in;
  unsigned short* out;
  int N;
  if (z == 0)      { in = Wq; out = Wcat;               N = 1024; }
  else if (z == 1) { in = Wo; out = Wot;                N = 1024; }
  else {
    if (bx < 2)      { in = Wk; out = Wcat + 1024 * 1024; N = 64; }
    else if (bx < 4) { in = Wv; out = Wcat + 1088 * 1024; N = 64; bx -= 2; }
    else return;
  }
  const int K = 1024;
  const int n0 = bx * 32, k0 = blockIdx.y * 32;
  const int tx = threadIdx.x, ty = threadIdx.y;  // block (32,8)
#pragma unroll
  for (int i = 0; i < 4; ++i)
    tile[ty + 8 * i][tx] = in[(size_t)(k0 + ty + 8 * i) * N + n0 + tx];
  __syncthreads();
#pragma unroll
  for (int i = 0; i < 4; ++i)
    out[(size_t)(n0 + ty + 8 * i) * K + k0 + tx] = f2bf(tile[tx][ty + 8 * i]);
}

// ---------- GEMM: C[M][N] = A[M][K](bf16) * Bt[N][K](bf16)^T ----------
// m97 structure + bijective XCD-aware block swizzle (grid %8 == 0).
template <int EPI>
__global__ __launch_bounds__(256) void gemm_bt(
    const unsigned short* __restrict__ A, const unsigned short* __restrict__ Bt,
    unsigned short* __restrict__ Cq, unsigned short* __restrict__ Ck,
    unsigned short* __restrict__ Cv, float* __restrict__ Cf, int N, int K) {
  __shared__ __align__(16) unsigned short As[128 * 64];
  __shared__ __align__(16) unsigned short Bs[128 * 64];
  const int tid = threadIdx.x;
  const int w = tid >> 6, lane = tid & 63;
  // XCD swizzle: consecutive post-swizzle ids share an A-panel per XCD
  const int nwg = gridDim.x * gridDim.y;
  const int lid = blockIdx.y * gridDim.x + blockIdx.x;
  const int cpx = nwg >> 3;
  const int swz = (lid & 7) * cpx + (lid >> 3);
  const int m0 = (swz / gridDim.x) * 128, n0 = (swz % gridDim.x) * 128;
  const int wm = (w >> 1) * 64, wn = (w & 1) * 64;
  const int g = lane >> 4, c = lane & 15;
  const int lr = lane >> 3, lc = (lane & 7) * 8;

  f32x4 acc[4][4] = {};

  for (int k0 = 0; k0 < K; k0 += 64) {
#pragma unroll
    for (int i = 0; i < 4; ++i) {
      int ci = w * 4 + i;  // 1KB chunk: rows 8ci..8ci+7
      GLDS16(A + (size_t)(m0 + ci * 8 + lr) * K + k0 + lc, As + ci * 512);
      GLDS16(Bt + (size_t)(n0 + ci * 8 + lr) * K + k0 + lc, Bs + ci * 512);
    }
    __syncthreads();
#pragma unroll
    for (int kk = 0; kk < 2; ++kk) {
      const int col = kk * 32 + g * 8;
      short8 av[4], bv[4];
#pragma unroll
      for (int mi = 0; mi < 4; ++mi)
        av[mi] = *(const short8*)(As + (wm + mi * 16 + c) * 64 + col);
#pragma unroll
      for (int ni = 0; ni < 4; ++ni)
        bv[ni] = *(const short8*)(Bs + (wn + ni * 16 + c) * 64 + col);
#pragma unroll
      for (int mi = 0; mi < 4; ++mi)
#pragma unroll
        for (int ni = 0; ni < 4; ++ni)
          acc[mi][ni] = __builtin_amdgcn_mfma_f32_16x16x32_bf16(
              av[mi], bv[ni], acc[mi][ni], 0, 0, 0);
    }
    __syncthreads();
  }

#pragma unroll
  for (int mi = 0; mi < 4; ++mi) {
#pragma unroll
    for (int ni = 0; ni < 4; ++ni) {
      f32x4 a = acc[mi][ni];
      const int col = n0 + wn + ni * 16 + c;
#pragma unroll
      for (int r = 0; r < 4; ++r) {
        const int row = m0 + wm + mi * 16 + g * 4 + r;
        float v = a[r];
        if (EPI == 0) {
          if (col < 1024)
            Cq[(size_t)row * 1024 + col] = f2bf(v * QSCALE);
          else if (col < 1088)
            Ck[(size_t)row * 64 + (col - 1024)] = f2bf(v);
          else  // V transposed: [b][d][t]
            Cv[((size_t)(row >> 11) * 64 + (col - 1088)) * 2048 + (row & 2047)] =
                f2bf(v);
        } else {
          Cf[(size_t)row * N + col] = v;
        }
      }
    }
  }
}

// ---------- causal multi-query flash attention, v5 ----------
// Swapped QK^T (lane-local softmax), defer-max THR=8 (log2 domain), l via
// ones-MFMA; max3 tree, strength-reduced staging ptrs, setprio on MFMA
// clusters. P-pack via scalar RNE casts (v_cvt_pk asm produced wrong bits
// on this toolchain; reverted — guide m240 says it's slower anyway).
__global__ __launch_bounds__(512, 4) void attn_mqa(
    const unsigned short* __restrict__ Q, const unsigned short* __restrict__ Kb,
    const unsigned short* __restrict__ Vt, unsigned short* __restrict__ Oc) {
  __shared__ __align__(16) unsigned short Kl[2][64 * 64];
  __shared__ __align__(16) unsigned short Vl[2][64 * 64];
  __shared__ __align__(16) unsigned short Pl[8][16 * 72];
  const int tid = threadIdx.x;
  const int w = tid >> 6, lane = tid & 63;
  const int pairi = blockIdx.x;   // 0..15
  const int hp = blockIdx.y;      // 0..7
  const int b = blockIdx.z;       // 0..3
  const int h = hp * 2 + (w >> 2);
  const int wq = w & 3;
  const int g = lane >> 4, c = lane & 15;
  const int swr = (c & 7) * 8;                    // read-side xor (shorts)
  const int srow = tid >> 3;                      // staging row 0..63
  const int scs = ((tid & 7) ^ (srow & 7)) * 8;   // swizzled source col
  const unsigned short* Kbase = Kb + (size_t)b * 2048 * 64;
  const unsigned short* Vbase = Vt + (size_t)b * 64 * 2048;
  unsigned short* pw = Pl[w];
  unsigned* pd = (unsigned*)pw;                   // dword view, row stride 36

  short8 ones;
#pragma unroll
  for (int j = 0; j < 8; ++j) ones[j] = (short)0x3F80;  // bf16 1.0

#pragma unroll 1
  for (int half = 0; half < 2; ++half) {
    const int qt = half ? (31 - pairi) : pairi;
    const int qb = qt * 64 + wq * 16;   // wave's first q row (global t)
    const int qi = qb + c;              // this lane's q row

    // Q fragments (B-operand: col=c, k=g*8+j), pre-scaled by QSCALE
    short8 qf[2];
#pragma unroll
    for (int kk = 0; kk < 2; ++kk)
      qf[kk] = *(const short8*)(Q + (size_t)(b * 2048 + qb + c) * 1024 +
                                h * 64 + kk * 32 + g * 8);

    f32x4 po[4] = {};
    f32x4 lac = {};
    float m = -1e30f;

    // prologue: stage tile 0 into buf 0; init running prefetch pointers
    GLDS16(Kbase + (size_t)srow * 64 + scs, &Kl[0][0] + tid * 8);
    GLDS16(Vbase + (size_t)srow * 2048 + scs, &Vl[0][0] + tid * 8);
    const unsigned short* kpf = Kbase + (size_t)(64 + srow) * 64 + scs;
    const unsigned short* vpf = Vbase + (size_t)srow * 2048 + 64 + scs;
    int cur = 0;

    for (int it = 0; it <= qt; ++it) {
      __syncthreads();  // buf[cur] staged; prev reads of cur^1 done

      if (it < qt) {    // prefetch next tile into cur^1 (overlaps compute)
        GLDS16(kpf, &Kl[cur ^ 1][0] + tid * 8);
        GLDS16(vpf, &Vl[cur ^ 1][0] + tid * 8);
        kpf += 64 * 64;
        vpf += 64;
      }

      const unsigned short* Kt = &Kl[cur][0];
      const unsigned short* Vc = &Vl[cur][0];
      const int kv0 = it * 64;

      // S^T = K Q^T: s[f] rows = kv (f*16 + g*4 + r), cols = q (c)
      f32x4 s[4] = {};
      __builtin_amdgcn_s_setprio(1);
#pragma unroll
      for (int kk = 0; kk < 2; ++kk) {
        const int col = (kk * 32 + g * 8) ^ swr;
#pragma unroll
        for (int f = 0; f < 4; ++f) {
          short8 kf = *(const short8*)(Kt + (f * 16 + c) * 64 + col);
          s[f] = __builtin_amdgcn_mfma_f32_16x16x32_bf16(kf, qf[kk], s[f], 0, 0, 0);
        }
      }
      __builtin_amdgcn_s_setprio(0);

      if (it == qt) {   // causal mask, diagonal tile only
#pragma unroll
        for (int f = 0; f < 4; ++f)
#pragma unroll
          for (int r = 0; r < 4; ++r)
            if (kv0 + f * 16 + g * 4 + r > qi) s[f][r] = -1e30f;
      }

      // lane-local max over 16 kv values (max3-fusable tree)
      const float t0 = fmaxf(fmaxf(s[0][0], s[0][1]), s[0][2]);
      const float t1 = fmaxf(fmaxf(s[0][3], s[1][0]), s[1][1]);
      const float t2 = fmaxf(fmaxf(s[1][2], s[1][3]), s[2][0]);
      const float t3 = fmaxf(fmaxf(s[2][1], s[2][2]), s[2][3]);
      const float t4 = fmaxf(fmaxf(s[3][0], s[3][1]), s[3][2]);
      const float u0 = fmaxf(fmaxf(t0, t1), t2);
      const float u1 = fmaxf(fmaxf(t3, t4), s[3][3]);
      float pm = fmaxf(u0, u1);

      // defer-max: rescale only when some row's max grew past THR=8 (log2)
      if (!__all(pm <= m + 8.0f)) {
        pm = fmaxf(pm, __shfl_xor(pm, 16, 64));
        pm = fmaxf(pm, __shfl_xor(pm, 32, 64));       // full max for q=c
        const float mn = fmaxf(m, pm);
        const float al = __builtin_amdgcn_exp2f(m - mn);  // alpha for q=c
        m = mn;
#pragma unroll
        for (int r = 0; r < 4; ++r) {
          const float ar = __shfl(al, g * 4 + r, 64);     // alpha for row g*4+r
          lac[r] *= ar;
#pragma unroll
          for (int fd = 0; fd < 4; ++fd) po[fd][r] *= ar;
        }
      }

      // P = exp2(S - m): pack pairs (RNE), bounce [q][kv] through wave LDS
#pragma unroll
      for (int f = 0; f < 4; ++f) {
        const float p0 = __builtin_amdgcn_exp2f(s[f][0] - m);
        const float p1 = __builtin_amdgcn_exp2f(s[f][1] - m);
        const float p2 = __builtin_amdgcn_exp2f(s[f][2] - m);
        const float p3 = __builtin_amdgcn_exp2f(s[f][3] - m);
        uint2 pk;
        pk.x = pack_bf2(p0, p1);
        pk.y = pack_bf2(p2, p3);
        *(uint2*)(pd + c * 36 + f * 8 + g * 2) = pk;
      }

      // O += P V ; l += P 1   (pa: A-frag P[q=c][kv=g*8+j+kk*32])
      __builtin_amdgcn_s_setprio(1);
#pragma unroll
      for (int kk = 0; kk < 2; ++kk) {
        short8 pa = *(const short8*)(pw + c * 72 + kk * 32 + g * 8);
        lac = __builtin_amdgcn_mfma_f32_16x16x32_bf16(pa, ones, lac, 0, 0, 0);
        const int col = (kk * 32 + g * 8) ^ swr;
#pragma unroll
        for (int fd = 0; fd < 4; ++fd) {
          short8 vf = *(const short8*)(Vc + (fd * 16 + c) * 64 + col);
          po[fd] = __builtin_amdgcn_mfma_f32_16x16x32_bf16(pa, vf, po[fd], 0, 0, 0);
        }
      }
      __builtin_amdgcn_s_setprio(0);
      cur ^= 1;
    }

    __syncthreads();  // protect K/V LDS before next half's prologue stage

    // epilogue: O / l  (l already in po row layout)
#pragma unroll
    for (int r = 0; r < 4; ++r) {
      const float inv = __builtin_amdgcn_rcpf(lac[r]);
      const int trow = qb + g * 4 + r;
#pragma unroll
      for (int fd = 0; fd < 4; ++fd)
        Oc[(size_t)(b * 2048 + trow) * 1024 + h * 64 + fd * 16 + c] =
            f2bf(po[fd][r] * inv);
    }
  }
}

// ---------- launch ----------
extern "C" void kernel_launch(void* const* d_in, const int* in_sizes, int n_in,
                              void* d_out, int out_size, void* d_ws,
                              size_t ws_size, hipStream_t stream) {
  const float* x = (const float*)d_in[0];
  const float* Wq = (const float*)d_in[1];
  const float* Wk = (const float*)d_in[2];
  const float* Wv = (const float*)d_in[3];
  const float* Wo = (const float*)d_in[4];
  float* out = (float*)d_out;

  char* ws = (char*)d_ws;
  unsigned short* xb   = (unsigned short*)ws;                          // 16 MB
  unsigned short* Qb   = (unsigned short*)(ws + (size_t)(16u << 20));  // 16 MB
  unsigned short* Attn = (unsigned short*)(ws + (size_t)(32u << 20));  // 16 MB
  unsigned short* Wcat = (unsigned short*)(ws + (size_t)(48u << 20));  // 2.25 MB
  unsigned short* Wot  = (unsigned short*)(ws + (size_t)(48u << 20) + 2359296);
  unsigned short* Kb   = (unsigned short*)(ws + (size_t)(48u << 20) + 2359296 + 2097152);
  unsigned short* Vtb  = (unsigned short*)(ws + (size_t)(48u << 20) + 2359296 + 2097152 + 1048576);

  // 1) cast x, fused weight transposes
  cast_x_bf16<<<8192, 256, 0, stream>>>((const float4*)x, (ushort4*)xb, 2097152);
  transpose_cvt_all<<<dim3(32, 32, 3), dim3(32, 8), 0, stream>>>(Wq, Wk, Wv, Wo,
                                                                 Wcat, Wot);

  // 2) fused QKV GEMM: [8192][1024] x [1152][1024]^T
  gemm_bt<0><<<dim3(9, 64), 256, 0, stream>>>(xb, Wcat, Qb, Kb, Vtb, nullptr,
                                              1152, 1024);

  // 3) causal MQA flash attention
  attn_mqa<<<dim3(16, 8, 4), 512, 0, stream>>>(Qb, Kb, Vtb, Attn);

  // 4) output projection: [8192][1024] x [1024][1024]^T -> fp32 d_out
  gemm_bt<1><<<dim3(8, 64), 256, 0, stream>>>(Attn, Wot, nullptr, nullptr,
                                              nullptr, out, 1024, 1024);
}

// Round 7
// 153.757 us; speedup vs baseline: 1.0018x; 1.0018x over previous
//
#include <hip/hip_runtime.h>

typedef __attribute__((ext_vector_type(8))) short short8;
typedef __attribute__((ext_vector_type(4))) float f32x4;

// ---------- helpers ----------
__device__ __forceinline__ unsigned short f2bf(float f) {
  unsigned u = __builtin_bit_cast(unsigned, f);
  u += 0x7fffu + ((u >> 16) & 1u);   // RNE
  return (unsigned short)(u >> 16);
}
// pack two f32 -> two bf16 (RTZ) in ONE v_perm_b32: bytes [p1.hi16 : p0.hi16]
__device__ __forceinline__ unsigned pack_bf2_rtz(float p0, float p1) {
  return __builtin_amdgcn_perm(__builtin_bit_cast(unsigned, p1),
                               __builtin_bit_cast(unsigned, p0), 0x07060302u);
}

#define GLDS16(g, l)                                                          \
  __builtin_amdgcn_global_load_lds(                                           \
      (const __attribute__((address_space(1))) void*)(g),                     \
      (__attribute__((address_space(3))) void*)(l), 16, 0, 0)

// Q pre-scale: HEAD_DIM^-0.5 * log2(e), so softmax uses exp2 directly.
#define QSCALE 0.18033688011112042f

// ---------- cast x (fp32 -> bf16), vectorized ----------
__global__ void cast_x_bf16(const float4* __restrict__ in,
                            ushort4* __restrict__ out, int n4) {
  int i = blockIdx.x * blockDim.x + threadIdx.x;
  if (i >= n4) return;
  float4 v = in[i];
  ushort4 o;
  o.x = f2bf(v.x); o.y = f2bf(v.y); o.z = f2bf(v.z); o.w = f2bf(v.w);
  out[i] = o;
}

// ---------- fused transpose+convert of all weights (one launch) ----------
__global__ void transpose_cvt_all(const float* __restrict__ Wq,
                                  const float* __restrict__ Wk,
                                  const float* __restrict__ Wv,
                                  const float* __restrict__ Wo,
                                  unsigned short* __restrict__ Wcat,
                                  unsigned short* __restrict__ Wot) {
  __shared__ float tile[32][33];
  const int z = blockIdx.z;
  int bx = blockIdx.x;
  const float* in;
  unsigned short* out;
  int N;
  if (z == 0)      { in = Wq; out = Wcat;               N = 1024; }
  else if (z == 1) { in = Wo; out = Wot;                N = 1024; }
  else {
    if (bx < 2)      { in = Wk; out = Wcat + 1024 * 1024; N = 64; }
    else if (bx < 4) { in = Wv; out = Wcat + 1088 * 1024; N = 64; bx -= 2; }
    else return;
  }
  const int K = 1024;
  const int n0 = bx * 32, k0 = blockIdx.y * 32;
  const int tx = threadIdx.x, ty = threadIdx.y;  // block (32,8)
#pragma unroll
  for (int i = 0; i < 4; ++i)
    tile[ty + 8 * i][tx] = in[(size_t)(k0 + ty + 8 * i) * N + n0 + tx];
  __syncthreads();
#pragma unroll
  for (int i = 0; i < 4; ++i)
    out[(size_t)(n0 + ty + 8 * i) * K + k0 + tx] = f2bf(tile[tx][ty + 8 * i]);
}

// ---------- transpose V: Vr [b*2048+t][64] -> Vt [b][64][2048] ----------
__global__ void transpose_v(const unsigned short* __restrict__ Vr,
                            unsigned short* __restrict__ Vt) {
  __shared__ unsigned short tile[32][34];
  const int t0 = blockIdx.x * 32;
  const int d0 = blockIdx.y * 32;
  const int b = blockIdx.z;
  const int tx = threadIdx.x, ty = threadIdx.y;  // block (32,8)
#pragma unroll
  for (int i = 0; i < 4; ++i)
    tile[ty + 8 * i][tx] =
        Vr[(size_t)(b * 2048 + t0 + ty + 8 * i) * 64 + d0 + tx];
  __syncthreads();
#pragma unroll
  for (int i = 0; i < 4; ++i)
    Vt[((size_t)b * 64 + d0 + ty + 8 * i) * 2048 + t0 + tx] =
        tile[tx][ty + 8 * i];
}

// ---------- GEMM: C[M][N] = A[M][K](bf16) * Bt[N][K](bf16)^T ----------
// m97 structure + bijective XCD-aware block swizzle (grid %8 == 0).
// EPI==0: QKV epilogue (col<1024 -> Q*QSCALE; col<1088 -> K [row][64];
//         else V coalesced [row][64] -> transposed later). EPI==1: fp32 C.
template <int EPI>
__global__ __launch_bounds__(256) void gemm_bt(
    const unsigned short* __restrict__ A, const unsigned short* __restrict__ Bt,
    unsigned short* __restrict__ Cq, unsigned short* __restrict__ Ck,
    unsigned short* __restrict__ Cv, float* __restrict__ Cf, int N, int K) {
  __shared__ __align__(16) unsigned short As[128 * 64];
  __shared__ __align__(16) unsigned short Bs[128 * 64];
  const int tid = threadIdx.x;
  const int w = tid >> 6, lane = tid & 63;
  const int nwg = gridDim.x * gridDim.y;
  const int lid = blockIdx.y * gridDim.x + blockIdx.x;
  const int cpx = nwg >> 3;
  const int swz = (lid & 7) * cpx + (lid >> 3);
  const int m0 = (swz / gridDim.x) * 128, n0 = (swz % gridDim.x) * 128;
  const int wm = (w >> 1) * 64, wn = (w & 1) * 64;
  const int g = lane >> 4, c = lane & 15;
  const int lr = lane >> 3, lc = (lane & 7) * 8;

  f32x4 acc[4][4] = {};

  for (int k0 = 0; k0 < K; k0 += 64) {
#pragma unroll
    for (int i = 0; i < 4; ++i) {
      int ci = w * 4 + i;  // 1KB chunk: rows 8ci..8ci+7
      GLDS16(A + (size_t)(m0 + ci * 8 + lr) * K + k0 + lc, As + ci * 512);
      GLDS16(Bt + (size_t)(n0 + ci * 8 + lr) * K + k0 + lc, Bs + ci * 512);
    }
    __syncthreads();
#pragma unroll
    for (int kk = 0; kk < 2; ++kk) {
      const int col = kk * 32 + g * 8;
      short8 av[4], bv[4];
#pragma unroll
      for (int mi = 0; mi < 4; ++mi)
        av[mi] = *(const short8*)(As + (wm + mi * 16 + c) * 64 + col);
#pragma unroll
      for (int ni = 0; ni < 4; ++ni)
        bv[ni] = *(const short8*)(Bs + (wn + ni * 16 + c) * 64 + col);
#pragma unroll
      for (int mi = 0; mi < 4; ++mi)
#pragma unroll
        for (int ni = 0; ni < 4; ++ni)
          acc[mi][ni] = __builtin_amdgcn_mfma_f32_16x16x32_bf16(
              av[mi], bv[ni], acc[mi][ni], 0, 0, 0);
    }
    __syncthreads();
  }

#pragma unroll
  for (int mi = 0; mi < 4; ++mi) {
#pragma unroll
    for (int ni = 0; ni < 4; ++ni) {
      f32x4 a = acc[mi][ni];
      const int col = n0 + wn + ni * 16 + c;
#pragma unroll
      for (int r = 0; r < 4; ++r) {
        const int row = m0 + wm + mi * 16 + g * 4 + r;
        float v = a[r];
        if (EPI == 0) {
          if (col < 1024)
            Cq[(size_t)row * 1024 + col] = f2bf(v * QSCALE);
          else if (col < 1088)
            Ck[(size_t)row * 64 + (col - 1024)] = f2bf(v);
          else  // V coalesced [row][64]; transposed by transpose_v
            Cv[(size_t)row * 64 + (col - 1088)] = f2bf(v);
        } else {
          Cf[(size_t)row * N + col] = v;
        }
      }
    }
  }
}

// ---------- causal multi-query flash attention, v6 ----------
// 1024-thr blocks (16 waves = 4 heads x 4 q-subtiles) sharing staged K/V;
// grid 512 flat, complement qt mapping (bid<256 -> qt=i, else 31-i) so
// co-resident blocks pair long+short. 2 blocks/CU -> 32 waves/CU.
// Swapped QK^T lane-local softmax; defer-max THR=8; l via ones-MFMA;
// P-pack via v_perm RTZ (1 instr / 2 values).
__global__ __launch_bounds__(1024, 8) void attn_mqa(
    const unsigned short* __restrict__ Q, const unsigned short* __restrict__ Kb,
    const unsigned short* __restrict__ Vt, unsigned short* __restrict__ Oc) {
  __shared__ __align__(16) unsigned short Kl[2][64 * 64];
  __shared__ __align__(16) unsigned short Vl[2][64 * 64];
  __shared__ __align__(16) unsigned short Pl[16][16 * 72];
  const int tid = threadIdx.x;
  const int w = tid >> 6, lane = tid & 63;
  const int bid = blockIdx.x;            // 0..511
  const int hq = (bid >> 2) & 3;         // head quad
  const int b = bid & 3;                 // batch
  const int qi16 = (bid >> 4) & 15;
  const int qt = (bid < 256) ? qi16 : 31 - qi16;
  const int h = hq * 4 + (w >> 2);
  const int wq = w & 3;
  const int g = lane >> 4, c = lane & 15;
  const int swr = (c & 7) * 8;            // read-side xor (shorts)
  // staging: waves 0-7 stage K, waves 8-15 stage V
  const int sh = tid >> 9;
  const int st = tid & 511;
  const int srow = st >> 3;               // 0..63
  const int scs = ((st & 7) ^ (srow & 7)) * 8;  // swizzled source col
  const unsigned short* Kbase = Kb + (size_t)b * 2048 * 64;
  const unsigned short* Vbase = Vt + (size_t)b * 64 * 2048;
  const unsigned short* sp = sh ? Vbase + (size_t)srow * 2048 + scs
                                : Kbase + (size_t)srow * 64 + scs;
  const ptrdiff_t sstep = sh ? 64 : 4096;
  unsigned short* ld0 = (sh ? &Vl[0][0] : &Kl[0][0]) + st * 8;
  unsigned short* ld1 = (sh ? &Vl[1][0] : &Kl[1][0]) + st * 8;
  unsigned short* pw = Pl[w];
  unsigned* pd = (unsigned*)pw;           // dword view, row stride 36

  short8 ones;
#pragma unroll
  for (int j = 0; j < 8; ++j) ones[j] = (short)0x3F80;  // bf16 1.0

  const int qb = qt * 64 + wq * 16;       // wave's first q row
  const int qi = qb + c;                  // this lane's q row

  // Q fragments (B-operand: col=c, k=g*8+j), pre-scaled by QSCALE
  short8 qf[2];
#pragma unroll
  for (int kk = 0; kk < 2; ++kk)
    qf[kk] = *(const short8*)(Q + (size_t)(b * 2048 + qb + c) * 1024 +
                              h * 64 + kk * 32 + g * 8);

  f32x4 po[4] = {};
  f32x4 lac = {};
  float m = -1e30f;

  // prologue: stage tile 0 into buf 0
  GLDS16(sp, ld0);
  sp += sstep;
  int cur = 0;

  for (int it = 0; it <= qt; ++it) {
    __syncthreads();  // buf[cur] staged; prev reads of cur^1 done

    if (it < qt) {    // prefetch next tile into cur^1 (overlaps compute)
      GLDS16(sp, cur ? ld0 : ld1);
      sp += sstep;
    }

    const unsigned short* Kt = &Kl[cur][0];
    const unsigned short* Vc = &Vl[cur][0];
    const int kv0 = it * 64;

    // S^T = K Q^T: s[f] rows = kv (f*16 + g*4 + r), cols = q (c)
    f32x4 s[4] = {};
    __builtin_amdgcn_s_setprio(1);
#pragma unroll
    for (int kk = 0; kk < 2; ++kk) {
      const int col = (kk * 32 + g * 8) ^ swr;
#pragma unroll
      for (int f = 0; f < 4; ++f) {
        short8 kf = *(const short8*)(Kt + (f * 16 + c) * 64 + col);
        s[f] = __builtin_amdgcn_mfma_f32_16x16x32_bf16(kf, qf[kk], s[f], 0, 0, 0);
      }
    }
    __builtin_amdgcn_s_setprio(0);

    if (it == qt) {   // causal mask, diagonal tile only
#pragma unroll
      for (int f = 0; f < 4; ++f)
#pragma unroll
        for (int r = 0; r < 4; ++r)
          if (kv0 + f * 16 + g * 4 + r > qi) s[f][r] = -1e30f;
    }

    // lane-local max over 16 kv values (max3-fusable tree)
    const float t0 = fmaxf(fmaxf(s[0][0], s[0][1]), s[0][2]);
    const float t1 = fmaxf(fmaxf(s[0][3], s[1][0]), s[1][1]);
    const float t2 = fmaxf(fmaxf(s[1][2], s[1][3]), s[2][0]);
    const float t3 = fmaxf(fmaxf(s[2][1], s[2][2]), s[2][3]);
    const float t4 = fmaxf(fmaxf(s[3][0], s[3][1]), s[3][2]);
    const float u0 = fmaxf(fmaxf(t0, t1), t2);
    const float u1 = fmaxf(fmaxf(t3, t4), s[3][3]);
    float pm = fmaxf(u0, u1);

    // defer-max: rescale only when some row's max grew past THR=8 (log2)
    if (!__all(pm <= m + 8.0f)) {
      pm = fmaxf(pm, __shfl_xor(pm, 16, 64));
      pm = fmaxf(pm, __shfl_xor(pm, 32, 64));       // full max for q=c
      const float mn = fmaxf(m, pm);
      const float al = __builtin_amdgcn_exp2f(m - mn);  // alpha for q=c
      m = mn;
#pragma unroll
      for (int r = 0; r < 4; ++r) {
        const float ar = __shfl(al, g * 4 + r, 64);     // alpha for row g*4+r
        lac[r] *= ar;
#pragma unroll
        for (int fd = 0; fd < 4; ++fd) po[fd][r] *= ar;
      }
    }

    // P = exp2(S - m): v_perm RTZ pack, bounce [q][kv] through wave LDS
#pragma unroll
    for (int f = 0; f < 4; ++f) {
      const float p0 = __builtin_amdgcn_exp2f(s[f][0] - m);
      const float p1 = __builtin_amdgcn_exp2f(s[f][1] - m);
      const float p2 = __builtin_amdgcn_exp2f(s[f][2] - m);
      const float p3 = __builtin_amdgcn_exp2f(s[f][3] - m);
      uint2 pk;
      pk.x = pack_bf2_rtz(p0, p1);
      pk.y = pack_bf2_rtz(p2, p3);
      *(uint2*)(pd + c * 36 + f * 8 + g * 2) = pk;
    }

    // O += P V ; l += P 1   (pa: A-frag P[q=c][kv=g*8+j+kk*32])
    __builtin_amdgcn_s_setprio(1);
#pragma unroll
    for (int kk = 0; kk < 2; ++kk) {
      short8 pa = *(const short8*)(pw + c * 72 + kk * 32 + g * 8);
      lac = __builtin_amdgcn_mfma_f32_16x16x32_bf16(pa, ones, lac, 0, 0, 0);
      const int col = (kk * 32 + g * 8) ^ swr;
#pragma unroll
      for (int fd = 0; fd < 4; ++fd) {
        short8 vf = *(const short8*)(Vc + (fd * 16 + c) * 64 + col);
        po[fd] = __builtin_amdgcn_mfma_f32_16x16x32_bf16(pa, vf, po[fd], 0, 0, 0);
      }
    }
    __builtin_amdgcn_s_setprio(0);
    cur ^= 1;
  }

  // epilogue: O / l  (l already in po row layout)
#pragma unroll
  for (int r = 0; r < 4; ++r) {
    const float inv = __builtin_amdgcn_rcpf(lac[r]);
    const int trow = qb + g * 4 + r;
#pragma unroll
    for (int fd = 0; fd < 4; ++fd)
      Oc[(size_t)(b * 2048 + trow) * 1024 + h * 64 + fd * 16 + c] =
          f2bf(po[fd][r] * inv);
  }
}

// ---------- launch ----------
extern "C" void kernel_launch(void* const* d_in, const int* in_sizes, int n_in,
                              void* d_out, int out_size, void* d_ws,
                              size_t ws_size, hipStream_t stream) {
  const float* x = (const float*)d_in[0];
  const float* Wq = (const float*)d_in[1];
  const float* Wk = (const float*)d_in[2];
  const float* Wv = (const float*)d_in[3];
  const float* Wo = (const float*)d_in[4];
  float* out = (float*)d_out;

  char* ws = (char*)d_ws;
  unsigned short* xb   = (unsigned short*)ws;                          // 16 MB
  unsigned short* Qb   = (unsigned short*)(ws + (size_t)(16u << 20));  // 16 MB
  unsigned short* Attn = (unsigned short*)(ws + (size_t)(32u << 20));  // 16 MB
  unsigned short* Wcat = (unsigned short*)(ws + (size_t)(48u << 20));  // 2.25 MB
  unsigned short* Wot  = (unsigned short*)(ws + (size_t)(48u << 20) + 2359296);
  unsigned short* Kb   = (unsigned short*)(ws + (size_t)(48u << 20) + 2359296 + 2097152);
  unsigned short* Vtb  = (unsigned short*)(ws + (size_t)(48u << 20) + 2359296 + 2097152 + 1048576);
  unsigned short* Vrow = Attn;  // V staging row-major; dead before attn writes O

  // 1) cast x, fused weight transposes
  cast_x_bf16<<<8192, 256, 0, stream>>>((const float4*)x, (ushort4*)xb, 2097152);
  transpose_cvt_all<<<dim3(32, 32, 3), dim3(32, 8), 0, stream>>>(Wq, Wk, Wv, Wo,
                                                                 Wcat, Wot);

  // 2) fused QKV GEMM (V written coalesced), then V transpose
  gemm_bt<0><<<dim3(9, 64), 256, 0, stream>>>(xb, Wcat, Qb, Kb, Vrow, nullptr,
                                              1152, 1024);
  transpose_v<<<dim3(64, 2, 4), dim3(32, 8), 0, stream>>>(Vrow, Vtb);

  // 3) causal MQA flash attention (16-wave blocks, 4 heads, complement qt)
  attn_mqa<<<512, 1024, 0, stream>>>(Qb, Kb, Vtb, Attn);

  // 4) output projection: [8192][1024] x [1024][1024]^T -> fp32 d_out
  gemm_bt<1><<<dim3(8, 64), 256, 0, stream>>>(Attn, Wot, nullptr, nullptr,
                                              nullptr, out, 1024, 1024);
}